// Round 5
// baseline (263.551 us; speedup 1.0000x reference)
//
#include <hip/hip_runtime.h>
#include <hip/hip_bf16.h>
#include <cstdint>
#include <cstddef>

#define BATCH 8192
#define IDIM  768
#define JDIM  768
#define GRID  5
#define KDIM  (IDIM * GRID)   // 3840
#define KC    (KDIM / 32)     // 120 k32-chunks
#define MT    (BATCH / 16)    // 512 m-tiles
#define NT    (JDIM / 16)     // 48 n-tiles

// ---------------- helpers ----------------

__device__ __forceinline__ unsigned short f2bf(float f) {
    unsigned int u = __float_as_uint(f);
    u += 0x7fffu + ((u >> 16) & 1u);
    return (unsigned short)(u >> 16);
}

typedef __bf16 bf16x8 __attribute__((ext_vector_type(8)));
typedef float  f32x4  __attribute__((ext_vector_type(4)));
typedef unsigned short ushortx8 __attribute__((ext_vector_type(8)));

// Fragment-shuffled operand layout (MFMA 16x16x32 bf16 A/B operand order):
//   value V[row][k]  ->  shuf[ (tile=row>>4) ][ kc=k>>5 ][ lane=(row&15)|(((k>>3)&3)<<4) ][ e=k&7 ]
// flat elem index = ((tile*KC + kc)*64 + lane)*8 + e
// A wave reads its whole fragment as ONE coalesced 1KB global_load_dwordx4 burst.

// ---------------- basis: A_shuf producer ----------------
// One wave produces one (bt, kc) fragment block: 16 b-rows x 32 k (single g).
// grid = dim3(KC, MT/4), 256 thr = 4 waves -> bt = blockIdx.y*4 + wave.

__global__ __launch_bounds__(256)
void basis_kernel(const float* __restrict__ x, unsigned short* __restrict__ Ashuf) {
    const int kc   = blockIdx.x;
    const int lane = threadIdx.x & 63;
    const int bt   = blockIdx.y * 4 + (threadIdx.x >> 6);
    const int g    = kc / 24;                  // 24 kc per g (768/32)
    const int ibase= (kc - g * 24) * 32;
    const float gv = -1.f + 0.5f * (float)g;

    const int b = bt * 16 + (lane & 15);
    const int i = ibase + (lane >> 4) * 8;
    const float4 x0 = *(const float4*)&x[(size_t)b * IDIM + i];
    const float4 x1 = *(const float4*)&x[(size_t)b * IDIM + i + 4];
    const float xs[8] = {x0.x, x0.y, x0.z, x0.w, x1.x, x1.y, x1.z, x1.w};

    ushortx8 o;
#pragma unroll
    for (int e = 0; e < 8; ++e) {
        const float e2 = __expf(2.f * xs[e]);                 // tanh via exp; saturates
        const float t  = 1.f - 2.f * __builtin_amdgcn_rcpf(e2 + 1.f);
        const float d  = t - gv;
        o[e] = f2bf(__expf(-5.f * d * d));
    }
    *(ushortx8*)&Ashuf[((size_t)(bt * KC + kc) * 64 + lane) * 8] = o;   // 1KB/wave, coalesced
}

// ---------------- Wt + bias: B_shuf producer ----------------
// blocks [0, NWT): one wave per (nt, kc) fragment block (16 j x 32 k, single g).
// blocks [NWT, NWT+NBIAS): bias[j] = sum_i shift[i,j].

#define NWT   (NT * KC / 4)        // 1440
#define NBIAS (JDIM / 64)          // 12

__global__ __launch_bounds__(256)
void wtbias_kernel(const float* __restrict__ coeffs,
                   const float* __restrict__ scale,
                   const float* __restrict__ shift,
                   unsigned short* __restrict__ Bshuf,
                   float* __restrict__ bias) {
    __shared__ float red[4][64];
    const int blk = blockIdx.x;
    const int t   = threadIdx.x;

    if (blk < NWT) {
        const int w    = blk * 4 + (t >> 6);      // wave id 0..5759
        const int lane = t & 63;
        const int nt   = w / KC;
        const int kc   = w - nt * KC;
        const int g    = kc / 24;
        const int ibase= (kc - g * 24) * 32;
        const int j    = nt * 16 + (lane & 15);
        const int i0   = ibase + (lane >> 4) * 8;
        ushortx8 o;
#pragma unroll
        for (int e = 0; e < 8; ++e) {
            const int i = i0 + e;
            const float c = coeffs[((size_t)i * JDIM + j) * GRID + g];
            const float s = scale[(size_t)i * JDIM + j];
            o[e] = f2bf(c * s);
        }
        *(ushortx8*)&Bshuf[((size_t)(nt * KC + kc) * 64 + lane) * 8] = o;
    } else {
        const int j0 = (blk - NWT) * 64;
        const int jj = t & 63;
        const int ip = t >> 6;
        float s = 0.f;
        for (int i = ip; i < IDIM; i += 4)
            s += shift[(size_t)i * JDIM + j0 + jj];
        red[ip][jj] = s;
        __syncthreads();
        if (t < 64)
            bias[j0 + t] = red[0][t] + red[1][t] + red[2][t] + red[3][t];
    }
}

// ---------------- MFMA GEMM v5: LDS-free, barrier-free ----------------
// BM=128 (8 mt), BN=96 (6 nt). Grid 8x64 = 512 blocks = 2/CU balanced.
// 4 waves, 2x2: each wave 64x48 (af 4, bf 3, 12 MFMAs per kc).
// Operands read straight from fragment-shuffled global layout (1KB coalesced
// loads, B L2-resident, A L3-resident). Register double-buffered prefetch;
// no __syncthreads anywhere in the loop.

__global__ __launch_bounds__(256, 2)
void kan_gemm(const unsigned short* __restrict__ Ashuf,
              const unsigned short* __restrict__ Bshuf,
              const float* __restrict__ bias,
              float* __restrict__ out) {
    const int t    = threadIdx.x;
    const int lane = t & 63;
    const int wave = t >> 6;
    const int mt0  = blockIdx.y * 8 + (wave >> 1) * 4;   // 4 m-tiles per wave
    const int nt0  = blockIdx.x * 6 + (wave & 1) * 3;    // 3 n-tiles per wave

    const unsigned short* pa[4];
    const unsigned short* pb[3];
#pragma unroll
    for (int f = 0; f < 4; ++f)
        pa[f] = Ashuf + ((size_t)(mt0 + f) * KC * 64 + lane) * 8;
#pragma unroll
    for (int f = 0; f < 3; ++f)
        pb[f] = Bshuf + ((size_t)(nt0 + f) * KC * 64 + lane) * 8;

    f32x4 acc[4][3] = {};
    bf16x8 a0[4], b0[3], a1[4], b1[3];

#define LOADF(A, B, kcv)                                                       \
    {                                                                          \
        _Pragma("unroll")                                                      \
        for (int f = 0; f < 4; ++f) A[f] = *(const bf16x8*)(pa[f] + (kcv) * 512); \
        _Pragma("unroll")                                                      \
        for (int f = 0; f < 3; ++f) B[f] = *(const bf16x8*)(pb[f] + (kcv) * 512); \
    }
#define MFMAS(A, B)                                                            \
    {                                                                          \
        _Pragma("unroll")                                                      \
        for (int fm = 0; fm < 4; ++fm)                                         \
            _Pragma("unroll")                                                  \
            for (int fn = 0; fn < 3; ++fn)                                     \
                acc[fm][fn] = __builtin_amdgcn_mfma_f32_16x16x32_bf16(         \
                    A[fm], B[fn], acc[fm][fn], 0, 0, 0);                       \
    }

    LOADF(a0, b0, 0);
    for (int kc = 0; kc < KC; kc += 2) {       // 60 iterations
        LOADF(a1, b1, kc + 1);                 // kc+1 <= 119
        MFMAS(a0, b0);
        const int kc2 = (kc + 2 < KC) ? kc + 2 : KC - 1;  // last load redundant
        LOADF(a0, b0, kc2);
        MFMAS(a1, b1);
    }
#undef LOADF
#undef MFMAS

    // epilogue: D mapping col=lane&15, row=(lane>>4)*4+reg  [measured m89/m91]
    const int col   = lane & 15;
    const int rbase = (lane >> 4) * 4;
#pragma unroll
    for (int fm = 0; fm < 4; ++fm) {
#pragma unroll
        for (int fn = 0; fn < 3; ++fn) {
            const int j  = (nt0 + fn) * 16 + col;
            const float bj = bias[j];
#pragma unroll
            for (int r = 0; r < 4; ++r) {
                const int row = (mt0 + fm) * 16 + rbase + r;
                out[(size_t)row * JDIM + j] = acc[fm][fn][r] + bj;
            }
        }
    }
}

// ---------------- fallback (ws too small): slow but correct ----------------

__global__ __launch_bounds__(256)
void fallback_kernel(const float* __restrict__ x,
                     const float* __restrict__ coeffs,
                     const float* __restrict__ scale,
                     const float* __restrict__ shift,
                     float* __restrict__ out) {
    __shared__ float bas[KDIM];
    const int b = blockIdx.x;
    const int t = threadIdx.x;
    for (int i = t; i < IDIM; i += 256) {
        float tv = tanhf(x[(size_t)b * IDIM + i]);
#pragma unroll
        for (int g = 0; g < GRID; ++g) {
            float d = tv - (-1.0f + 0.5f * (float)g);
            bas[g * IDIM + i] = __expf(-5.0f * d * d);
        }
    }
    __syncthreads();
#pragma unroll
    for (int jj = 0; jj < 3; ++jj) {
        const int j = t + jj * 256;
        float acc = 0.f;
        for (int i = 0; i < IDIM; ++i) {
            const float sc = scale[(size_t)i * JDIM + j];
            const float* cp = &coeffs[((size_t)i * JDIM + j) * GRID];
            float s5 = 0.f;
#pragma unroll
            for (int g = 0; g < GRID; ++g) s5 += bas[g * IDIM + i] * cp[g];
            acc += s5 * sc + shift[(size_t)i * JDIM + j];
        }
        out[(size_t)b * JDIM + j] = acc;
    }
}

// ---------------- launch ----------------

extern "C" void kernel_launch(void* const* d_in, const int* in_sizes, int n_in,
                              void* d_out, int out_size, void* d_ws, size_t ws_size,
                              hipStream_t stream) {
    const float* x      = (const float*)d_in[0];
    const float* coeffs = (const float*)d_in[1];
    const float* scale  = (const float*)d_in[2];
    const float* shift  = (const float*)d_in[3];
    float* out = (float*)d_out;

    const size_t wt_bytes   = (size_t)JDIM * KDIM * sizeof(unsigned short); // 5,898,240
    const size_t bias_off   = wt_bytes;
    const size_t bias_bytes = (size_t)JDIM * sizeof(float);
    const size_t bas_off    = bias_off + bias_bytes;
    const size_t bas_bytes  = (size_t)BATCH * KDIM * sizeof(unsigned short);
    const size_t need       = bas_off + bas_bytes;                          // ~68.8 MB

    if (ws_size >= need) {
        unsigned short* Bshuf = (unsigned short*)d_ws;
        float*          bias  = (float*)((char*)d_ws + bias_off);
        unsigned short* Ashuf = (unsigned short*)((char*)d_ws + bas_off);

        basis_kernel<<<dim3(KC, MT / 4), 256, 0, stream>>>(x, Ashuf);
        wtbias_kernel<<<NWT + NBIAS, 256, 0, stream>>>(coeffs, scale, shift, Bshuf, bias);
        kan_gemm<<<dim3(JDIM / 96, BATCH / 128), 256, 0, stream>>>(Ashuf, Bshuf, bias, out);
    } else {
        fallback_kernel<<<BATCH, 256, 0, stream>>>(x, coeffs, scale, shift, out);
    }
}